// Round 4
// baseline (171.849 us; speedup 1.0000x reference)
//
#include <hip/hip_runtime.h>
#include <math.h>

// Problem constants (B=8, M=1024, P=256, N=4096)
#define R_ROWS 8192   // B*M rows of X-side
#define NP     4096   // train points
#define DREAL  257    // P+1
#define DPAD   288    // padded to multiple of 32 for BK

#define BM 128
#define BN 128
#define BK 32
#define LDSS 32       // packed rows (global_load_lds-compatible; even bank spread)
#define NBLKX (R_ROWS / BM)   // 64
#define NBLKY (NP / BN)       // 32
#define QGRID (NBLKX * NBLKY) // 2048

using frag8 = __attribute__((ext_vector_type(8))) short;
using f32x4 = __attribute__((ext_vector_type(4))) float;

static __device__ __forceinline__ float bf2f(unsigned short u) {
    return __uint_as_float(((unsigned int)u) << 16);
}
static __device__ __forceinline__ unsigned short f2bf(float f) {
    unsigned int u = __float_as_uint(f);
    unsigned int lsb = (u >> 16) & 1u;
    u += 0x7fffu + lsb;           // round-to-nearest-even
    return (unsigned short)(u >> 16);
}

// async global->LDS, 16B per lane; lds base must be wave-uniform (lane i -> base + i*16B)
static __device__ __forceinline__ void gll16(const unsigned short* g, unsigned short* l) {
    __builtin_amdgcn_global_load_lds(
        (const __attribute__((address_space(1))) unsigned int*)g,
        (__attribute__((address_space(3))) unsigned int*)l, 16, 0, 0);
}

// ---- prep: bf16 [row][DPAD] features + fp32 norms + workspace zeroing ----
__global__ void prep_all(const float* __restrict__ X, const int* __restrict__ A,
                         const float* __restrict__ Z,
                         unsigned short* __restrict__ XAb, unsigned short* __restrict__ Zb,
                         float* __restrict__ x2, float* __restrict__ z2,
                         char* __restrict__ zreg,   // [q_acc|rowflag|tileflag|ctr] 41472 B
                         float* __restrict__ out) {
    int b = blockIdx.x;
    int tid = threadIdx.x;
    // fold zeroing of accumulators/flags + f_loc output region into this kernel
    uint4 zz = {0, 0, 0, 0};
    if (b < 11) {
        int off = b * 4096 + tid * 16;
        if (off < 41472) *(uint4*)(zreg + off) = zz;
    } else if (b < 19) {
        int off = (b - 11) * 4096 + tid * 16;
        *(uint4*)((char*)out + off) = zz;          // out[0:8192] = 0 (f_loc accum)
    }

    int row  = b * 4 + (tid >> 6);
    int lane = tid & 63;
    float s = 0.f;
    if (row < R_ROWS) {
        const float* xr = X + (size_t)row * 256;
        unsigned short* o = XAb + (size_t)row * DPAD;
#pragma unroll
        for (int i = 0; i < 4; i++) {
            float v = xr[lane + 64 * i];
            s += v * v;
            o[lane + 64 * i] = f2bf(v);
        }
        if (lane == 0) {
            float a = (float)A[row];
            o[256] = f2bf(a);
            s += a * a;
        }
        if (lane >= 33) o[257 + (lane - 33)] = 0;   // zero pad 257..287
#pragma unroll
        for (int off = 32; off; off >>= 1) s += __shfl_down(s, off, 64);
        if (lane == 0) x2[row] = s;
    } else {
        int zr_i = row - R_ROWS;
        if (zr_i >= NP) return;
        const float* zr = Z + (size_t)zr_i * DREAL;
        unsigned short* o = Zb + (size_t)zr_i * DPAD;
#pragma unroll
        for (int i = 0; i < 4; i++) {
            float v = zr[lane + 64 * i];
            s += v * v;
            o[lane + 64 * i] = f2bf(v);
        }
        if (lane < 32) {
            int idx = 256 + lane;
            float v = (idx < DREAL) ? zr[idx] : 0.f;
            s += v * v;
            o[idx] = f2bf(v);
        }
#pragma unroll
        for (int off = 32; off; off >>= 1) s += __shfl_down(s, off, 64);
        if (lane == 0) z2[zr_i] = s;
    }
}

// ---- Kxz tile kernel: GEMM + zero-screen; exact epilogue only when needed ----
__global__ __launch_bounds__(256, 4) void gemm_kxz(
    const unsigned short* __restrict__ Abuf,  // [R_ROWS][DPAD]
    const unsigned short* __restrict__ Bbuf,  // [NP][DPAD]
    const float* __restrict__ x2, const float* __restrict__ z2,
    const float* __restrict__ alpha,
    unsigned short* __restrict__ Kb,          // [R_ROWS][NP] (tiles written only if needed)
    float* __restrict__ floc_out,             // [R_ROWS] pre-zeroed; atomic accum
    int* __restrict__ rowflag, int* __restrict__ tileflag)
{
    __shared__ unsigned short sA[BM * LDSS];
    __shared__ unsigned short sB[BN * LDSS];
    __shared__ int sAnyW[4];
    const int m0 = blockIdx.x * BM, n0 = blockIdx.y * BN;
    const int tid = threadIdx.x, lane = tid & 63, wave = tid >> 6;
    const int wr = wave >> 1, wc = wave & 1;
    const int q = lane >> 4, rr = lane & 15;
    const int grow = lane >> 2, gcol = (lane & 3) * 8;   // async staging lane map

    f32x4 acc[4][4] = {};
    for (int kk = 0; kk < DPAD; kk += BK) {
#pragma unroll
        for (int c = 0; c < 2; c++) {
            int r = wave * 32 + c * 16 + grow;
            gll16(Abuf + (size_t)(m0 + r) * DPAD + kk + gcol, &sA[(wave * 32 + c * 16) * LDSS]);
            gll16(Bbuf + (size_t)(n0 + r) * DPAD + kk + gcol, &sB[(wave * 32 + c * 16) * LDSS]);
        }
        __syncthreads();
        frag8 af[4], bfr[4];
#pragma unroll
        for (int i = 0; i < 4; i++) {
            af[i]  = *(const frag8*)(&sA[(wr * 64 + i * 16 + rr) * LDSS + q * 8]);
            bfr[i] = *(const frag8*)(&sB[(wc * 64 + i * 16 + rr) * LDSS + q * 8]);
        }
#pragma unroll
        for (int i = 0; i < 4; i++)
#pragma unroll
            for (int j = 0; j < 4; j++)
                acc[i][j] = __builtin_amdgcn_mfma_f32_16x16x32_bf16(af[i], bfr[j], acc[i][j], 0, 0, 0);
        __syncthreads();
    }
    // ---- zero screen: bv==0 exactly iff d >= ~185.7 (bf16 half-min-subnormal) ----
    float zn[4];
#pragma unroll
    for (int j = 0; j < 4; j++) zn[j] = z2[n0 + wc * 64 + j * 16 + rr];
    bool anyl = false;
#pragma unroll
    for (int i = 0; i < 4; i++)
#pragma unroll
        for (int reg = 0; reg < 4; reg++) {
            float x = x2[m0 + wr * 64 + i * 16 + q * 4 + reg];
#pragma unroll
            for (int j = 0; j < 4; j++) {
                float d = x + zn[j] - 2.0f * acc[i][j][reg];
                anyl |= !(d >= 186.0f);    // NaN-safe: NaN -> slow path
            }
        }
    unsigned long long wb = __ballot(anyl);
    if (lane == 0) sAnyW[wave] = (wb != 0ULL) ? 1 : 0;
    __syncthreads();
    if (sAnyW[0] | sAnyW[1] | sAnyW[2] | sAnyW[3]) {
        // exact epilogue (rare path): exp, Kb write, fused f_loc, flags
        float av[4];
#pragma unroll
        for (int j = 0; j < 4; j++) av[j] = alpha[n0 + wc * 64 + j * 16 + rr];
        unsigned int wany = 0;
#pragma unroll
        for (int i = 0; i < 4; i++) {
#pragma unroll
            for (int reg = 0; reg < 4; reg++) {
                int ml = wr * 64 + i * 16 + q * 4 + reg;
                float x = x2[m0 + ml];
                float s = 0.f;
#pragma unroll
                for (int j = 0; j < 4; j++) {
                    float d = fmaxf(x + zn[j] - 2.0f * acc[i][j][reg], 0.0f);
                    unsigned short bv = f2bf(__expf(-0.5f * d));
                    wany |= bv;
                    Kb[(size_t)(m0 + ml) * NP + n0 + wc * 64 + j * 16 + rr] = bv;
                    s += bf2f(bv) * av[j];
                }
                s += __shfl_xor(s, 1, 64);
                s += __shfl_xor(s, 2, 64);
                s += __shfl_xor(s, 4, 64);
                s += __shfl_xor(s, 8, 64);
                if (rr == 0 && s != 0.0f) atomicAdd(&floc_out[m0 + ml], s);
            }
        }
        unsigned long long b2 = __ballot(wany != 0);
        if (lane == 0 && b2 != 0ULL) {
            atomicOr(&tileflag[blockIdx.x * NBLKY + blockIdx.y], 1);
            atomicOr(&rowflag[blockIdx.x], 1);
        }
    }
}

// ---- q[m] += sum_t (sum_n Kb[m][n]*bf16(Kinv[t][n])) * Kb[m][t]; fused finalize ----
__global__ __launch_bounds__(256, 4) void gemm_q(
    const unsigned short* __restrict__ Kb,   // [R_ROWS][NP] bf16 (sparse-tiled)
    const float* __restrict__ Kinv,          // [NP][NP] fp32, cast during staging
    float* __restrict__ q_acc,
    const int* __restrict__ rowflag, const int* __restrict__ tileflag,
    unsigned int* __restrict__ done_ctr,
    float* __restrict__ out)
{
    __shared__ unsigned short sA[BM * LDSS];
    __shared__ unsigned short sB[BN * LDSS];
    __shared__ int sLast;
    const int m0 = blockIdx.x * BM, t0 = blockIdx.y * BN;
    const int tid = threadIdx.x, lane = tid & 63, wave = tid >> 6;
    const int wr = wave >> 1, wc = wave & 1;
    const int q = lane >> 4, rr = lane & 15;
    const int grow = lane >> 2, gcol = (lane & 3) * 8;
    const bool active = rowflag[blockIdx.x] != 0;

    if (active) {
        f32x4 acc[4][4] = {};
        const int mblk = blockIdx.x * NBLKY;
        for (int kb = 0; kb < NBLKY; kb++) {
            if (tileflag[mblk + kb] == 0) continue;   // A-tile exactly zero: skip
            int kk0 = kb * BN;
#pragma unroll
            for (int k2 = 0; k2 < BN; k2 += BK) {
                int kk = kk0 + k2;
#pragma unroll
                for (int c = 0; c < 2; c++) {
                    int rl = wave * 32 + c * 16 + grow;
                    gll16(Kb + (size_t)(m0 + rl) * NP + kk + gcol,
                          &sA[(wave * 32 + c * 16) * LDSS]);
                    // B: fp32 -> bf16 cast through VGPRs (even bank-group layout)
                    const float* gp = Kinv + (size_t)(t0 + rl) * NP + kk + gcol;
                    float4 v0 = *(const float4*)gp;
                    float4 v1 = *(const float4*)(gp + 4);
                    unsigned short tmp[8];
                    tmp[0] = f2bf(v0.x); tmp[1] = f2bf(v0.y);
                    tmp[2] = f2bf(v0.z); tmp[3] = f2bf(v0.w);
                    tmp[4] = f2bf(v1.x); tmp[5] = f2bf(v1.y);
                    tmp[6] = f2bf(v1.z); tmp[7] = f2bf(v1.w);
                    *(uint4*)(&sB[rl * LDSS + gcol]) = *(const uint4*)tmp;
                }
                __syncthreads();
                frag8 af[4], bfr[4];
#pragma unroll
                for (int i = 0; i < 4; i++) {
                    af[i]  = *(const frag8*)(&sA[(wr * 64 + i * 16 + rr) * LDSS + q * 8]);
                    bfr[i] = *(const frag8*)(&sB[(wc * 64 + i * 16 + rr) * LDSS + q * 8]);
                }
#pragma unroll
                for (int i = 0; i < 4; i++)
#pragma unroll
                    for (int j = 0; j < 4; j++)
                        acc[i][j] = __builtin_amdgcn_mfma_f32_16x16x32_bf16(af[i], bfr[j], acc[i][j], 0, 0, 0);
                __syncthreads();
            }
        }
        if (tileflag[mblk + blockIdx.y] != 0) {   // Kb[m][t] block nonzero
#pragma unroll
            for (int i = 0; i < 4; i++) {
#pragma unroll
                for (int reg = 0; reg < 4; reg++) {
                    int m = m0 + wr * 64 + i * 16 + q * 4 + reg;
                    float s = 0.f;
#pragma unroll
                    for (int j = 0; j < 4; j++) {
                        int t = t0 + wc * 64 + j * 16 + rr;
                        s += acc[i][j][reg] * bf2f(Kb[(size_t)m * NP + t]);
                    }
                    s += __shfl_xor(s, 1, 64);
                    s += __shfl_xor(s, 2, 64);
                    s += __shfl_xor(s, 4, 64);
                    s += __shfl_xor(s, 8, 64);
                    if (rr == 0 && s != 0.0f) atomicAdd(&q_acc[m], s);
                }
            }
        }
        __threadfence();   // release q_acc atomics before the done-counter bump
    }
    // ---- fused finalize: last block writes f_var = 1 - q ----
    __syncthreads();
    if (tid == 0) {
        unsigned int old = atomicAdd(done_ctr, 1u);
        sLast = (old == QGRID - 1) ? 1 : 0;
    }
    __syncthreads();
    if (sLast) {
        for (int m = tid; m < R_ROWS; m += 256) {
            float v = __hip_atomic_load(&q_acc[m], __ATOMIC_RELAXED, __HIP_MEMORY_SCOPE_AGENT);
            out[R_ROWS + m] = 1.0f - v;
        }
    }
}

extern "C" void kernel_launch(void* const* d_in, const int* in_sizes, int n_in,
                              void* d_out, int out_size, void* d_ws, size_t ws_size,
                              hipStream_t stream) {
    const float* X     = (const float*)d_in[0];
    const int*   A     = (const int*)d_in[1];
    const float* Z     = (const float*)d_in[2];   // XA_train [4096][257]
    const float* alpha = (const float*)d_in[3];
    const float* Kinv  = (const float*)d_in[4];
    float* out = (float*)d_out;

    // workspace carve; total ~74.3 MB
    char* ws = (char*)d_ws;
    unsigned short* XAb = (unsigned short*)(ws);                 //  4,718,592 B
    unsigned short* Zb  = (unsigned short*)(ws + 4718592);       //  2,359,296 B
    float* x2       = (float*)(ws + 7077888);                    //     32,768 B
    float* z2       = (float*)(ws + 7110656);                    //     16,384 B
    // contiguous zero region: q_acc | rowflag | tileflag | done_ctr = 41,472 B
    float*        q_acc    = (float*)(ws + 7127040);             //     32,768 B
    int*          rowflag  = (int*)  (ws + 7159808);             //        256 B
    int*          tileflag = (int*)  (ws + 7160064);             //      8,192 B
    unsigned int* done_ctr = (unsigned int*)(ws + 7168256);      //        256 B
    unsigned short* Kb = (unsigned short*)(ws + 7168512);        // 67,108,864 B

    prep_all<<<(R_ROWS + NP) / 4, 256, 0, stream>>>(X, A, Z, XAb, Zb, x2, z2,
                                                    (char*)q_acc, out);
    gemm_kxz<<<dim3(NBLKX, NBLKY), 256, 0, stream>>>(XAb, Zb, x2, z2, alpha, Kb,
                                                     out, rowflag, tileflag);
    gemm_q<<<dim3(NBLKX, NBLKY), 256, 0, stream>>>(Kb, Kinv, q_acc, rowflag, tileflag,
                                                   done_ctr, out);
}

// Round 5
// 130.441 us; speedup vs baseline: 1.3175x; 1.3175x over previous
//
#include <hip/hip_runtime.h>
#include <math.h>

// Problem constants (B=8, M=1024, P=256, N=4096)
#define R_ROWS 8192   // B*M rows of X-side
#define NP     4096   // train points
#define DREAL  257    // P+1
#define DPAD   288    // padded: 3 x 96 (K-slabs of 96 = 3 sub-tiles of 32)

#define BM 128
#define BN 128
#define BK 32
#define LDSS 32       // packed rows (global_load_lds-compatible)
#define NBLKX (R_ROWS / BM)   // 64
#define NBLKY (NP / BN)       // 32

using frag8 = __attribute__((ext_vector_type(8))) short;
using f32x4 = __attribute__((ext_vector_type(4))) float;

static __device__ __forceinline__ float bf2f(unsigned short u) {
    return __uint_as_float(((unsigned int)u) << 16);
}
static __device__ __forceinline__ unsigned short f2bf(float f) {
    unsigned int u = __float_as_uint(f);
    unsigned int lsb = (u >> 16) & 1u;
    u += 0x7fffu + lsb;           // round-to-nearest-even
    return (unsigned short)(u >> 16);
}

// async global->LDS, 16B per lane; lds base wave-uniform (lane i -> base + i*16B)
static __device__ __forceinline__ void gll16(const unsigned short* g, unsigned short* l) {
    __builtin_amdgcn_global_load_lds(
        (const __attribute__((address_space(1))) unsigned int*)g,
        (__attribute__((address_space(3))) unsigned int*)l, 16, 0, 0);
}

// ---- prep: bf16 [row][DPAD] features + fp32 norms + workspace zeroing ----
__global__ void prep_all(const float* __restrict__ X, const int* __restrict__ A,
                         const float* __restrict__ Z,
                         unsigned short* __restrict__ XAb, unsigned short* __restrict__ Zb,
                         float* __restrict__ x2, float* __restrict__ z2,
                         char* __restrict__ zreg,   // [q_acc|rowflag|tileflag] 41472 B
                         float* __restrict__ out) {
    int b = blockIdx.x;
    int tid = threadIdx.x;
    uint4 zz = {0, 0, 0, 0};
    if (b < 11) {
        int off = b * 4096 + tid * 16;
        if (off < 41472) *(uint4*)(zreg + off) = zz;
    } else if (b < 19) {
        int off = (b - 11) * 4096 + tid * 16;
        *(uint4*)((char*)out + off) = zz;          // out[0:8192] = 0 (f_loc accum)
    }

    int row  = b * 4 + (tid >> 6);
    int lane = tid & 63;
    float s = 0.f;
    if (row < R_ROWS) {
        const float* xr = X + (size_t)row * 256;
        unsigned short* o = XAb + (size_t)row * DPAD;
#pragma unroll
        for (int i = 0; i < 4; i++) {
            float v = xr[lane + 64 * i];
            s += v * v;
            o[lane + 64 * i] = f2bf(v);
        }
        if (lane == 0) {
            float a = (float)A[row];
            o[256] = f2bf(a);
            s += a * a;
        }
        if (lane >= 33) o[257 + (lane - 33)] = 0;   // zero pad 257..287
#pragma unroll
        for (int off = 32; off; off >>= 1) s += __shfl_down(s, off, 64);
        if (lane == 0) x2[row] = s;
    } else {
        int zr_i = row - R_ROWS;
        if (zr_i >= NP) return;
        const float* zr = Z + (size_t)zr_i * DREAL;
        unsigned short* o = Zb + (size_t)zr_i * DPAD;
#pragma unroll
        for (int i = 0; i < 4; i++) {
            float v = zr[lane + 64 * i];
            s += v * v;
            o[lane + 64 * i] = f2bf(v);
        }
        if (lane < 32) {
            int idx = 256 + lane;
            float v = (idx < DREAL) ? zr[idx] : 0.f;
            s += v * v;
            o[idx] = f2bf(v);
        }
#pragma unroll
        for (int off = 32; off; off >>= 1) s += __shfl_down(s, off, 64);
        if (lane == 0) z2[zr_i] = s;
    }
}

// ---- Kxz tile kernel: 3-slot staging (48 MFMA/barrier), zero-screen epilogue ----
__global__ __launch_bounds__(256, 3) void gemm_kxz(
    const unsigned short* __restrict__ Abuf,  // [R_ROWS][DPAD]
    const unsigned short* __restrict__ Bbuf,  // [NP][DPAD]
    const float* __restrict__ x2, const float* __restrict__ z2,
    const float* __restrict__ alpha,
    unsigned short* __restrict__ Kb,          // [R_ROWS][NP] (written only if needed)
    float* __restrict__ floc_out,             // [R_ROWS] pre-zeroed; atomic accum
    int* __restrict__ rowflag, int* __restrict__ tileflag)
{
    __shared__ unsigned short sA[3][BM * LDSS];   // 3 x 8 KB
    __shared__ unsigned short sB[3][BN * LDSS];   // 3 x 8 KB
    __shared__ int sAnyW[4];
    const int m0 = blockIdx.x * BM, n0 = blockIdx.y * BN;
    const int tid = threadIdx.x, lane = tid & 63, wave = tid >> 6;
    const int wr = wave >> 1, wc = wave & 1;
    const int q = lane >> 4, rr = lane & 15;
    const int grow = lane >> 2, gcol = (lane & 3) * 8;   // async staging lane map

    f32x4 acc[4][4] = {};
    for (int kk = 0; kk < DPAD; kk += 3 * BK) {     // 3 outer iterations
#pragma unroll
        for (int s3 = 0; s3 < 3; s3++) {
            int ks = kk + s3 * BK;
#pragma unroll
            for (int c = 0; c < 2; c++) {
                int r = wave * 32 + c * 16 + grow;
                unsigned short* la = &sA[s3][(wave * 32 + c * 16) * LDSS];
                unsigned short* lb = &sB[s3][(wave * 32 + c * 16) * LDSS];
                gll16(Abuf + (size_t)(m0 + r) * DPAD + ks + gcol, la);
                gll16(Bbuf + (size_t)(n0 + r) * DPAD + ks + gcol, lb);
            }
        }
        __syncthreads();
#pragma unroll
        for (int s3 = 0; s3 < 3; s3++) {
            frag8 af[4], bfr[4];
#pragma unroll
            for (int i = 0; i < 4; i++) {
                af[i]  = *(const frag8*)(&sA[s3][(wr * 64 + i * 16 + rr) * LDSS + q * 8]);
                bfr[i] = *(const frag8*)(&sB[s3][(wc * 64 + i * 16 + rr) * LDSS + q * 8]);
            }
#pragma unroll
            for (int i = 0; i < 4; i++)
#pragma unroll
                for (int j = 0; j < 4; j++)
                    acc[i][j] = __builtin_amdgcn_mfma_f32_16x16x32_bf16(af[i], bfr[j], acc[i][j], 0, 0, 0);
        }
        __syncthreads();
    }
    // ---- zero screen: bv==0 exactly iff d >= ~185.7 (half bf16 min-subnormal) ----
    float zn[4];
#pragma unroll
    for (int j = 0; j < 4; j++) zn[j] = z2[n0 + wc * 64 + j * 16 + rr];
    bool anyl = false;
#pragma unroll
    for (int i = 0; i < 4; i++)
#pragma unroll
        for (int reg = 0; reg < 4; reg++) {
            float x = x2[m0 + wr * 64 + i * 16 + q * 4 + reg];
#pragma unroll
            for (int j = 0; j < 4; j++) {
                float d = x + zn[j] - 2.0f * acc[i][j][reg];
                anyl |= !(d >= 186.0f);    // NaN-safe: NaN -> slow path
            }
        }
    unsigned long long wb = __ballot(anyl);
    if (lane == 0) sAnyW[wave] = (wb != 0ULL) ? 1 : 0;
    __syncthreads();
    if (sAnyW[0] | sAnyW[1] | sAnyW[2] | sAnyW[3]) {
        // exact epilogue (rare path): exp, Kb write, fused f_loc, flags
        float av[4];
#pragma unroll
        for (int j = 0; j < 4; j++) av[j] = alpha[n0 + wc * 64 + j * 16 + rr];
        unsigned int wany = 0;
#pragma unroll
        for (int i = 0; i < 4; i++) {
#pragma unroll
            for (int reg = 0; reg < 4; reg++) {
                int ml = wr * 64 + i * 16 + q * 4 + reg;
                float x = x2[m0 + ml];
                float s = 0.f;
#pragma unroll
                for (int j = 0; j < 4; j++) {
                    float d = fmaxf(x + zn[j] - 2.0f * acc[i][j][reg], 0.0f);
                    unsigned short bv = f2bf(__expf(-0.5f * d));
                    wany |= bv;
                    Kb[(size_t)(m0 + ml) * NP + n0 + wc * 64 + j * 16 + rr] = bv;
                    s += bf2f(bv) * av[j];
                }
                s += __shfl_xor(s, 1, 64);
                s += __shfl_xor(s, 2, 64);
                s += __shfl_xor(s, 4, 64);
                s += __shfl_xor(s, 8, 64);
                if (rr == 0 && s != 0.0f) atomicAdd(&floc_out[m0 + ml], s);
            }
        }
        unsigned long long b2 = __ballot(wany != 0);
        if (lane == 0 && b2 != 0ULL) {
            atomicOr(&tileflag[blockIdx.x * NBLKY + blockIdx.y], 1);
            atomicOr(&rowflag[blockIdx.x], 1);
        }
    }
}

// ---- q[m] += sum_t (sum_n Kb[m][n]*bf16(Kinv[t][n])) * Kb[m][t]; tile-gated ----
__global__ __launch_bounds__(256, 4) void gemm_q(
    const unsigned short* __restrict__ Kb,   // [R_ROWS][NP] bf16 (sparse-tiled)
    const float* __restrict__ Kinv,          // [NP][NP] fp32, cast during staging
    float* __restrict__ q_acc,
    const int* __restrict__ rowflag, const int* __restrict__ tileflag)
{
    const int m0 = blockIdx.x * BM, t0 = blockIdx.y * BN;
    if (rowflag[blockIdx.x] == 0) return;    // entire A row-block zero -> exact 0

    __shared__ unsigned short sA[BM * LDSS];
    __shared__ unsigned short sB[BN * LDSS];
    const int tid = threadIdx.x, lane = tid & 63, wave = tid >> 6;
    const int wr = wave >> 1, wc = wave & 1;
    const int q = lane >> 4, rr = lane & 15;
    const int grow = lane >> 2, gcol = (lane & 3) * 8;
    const int mblk = blockIdx.x * NBLKY;

    f32x4 acc[4][4] = {};
    for (int kb = 0; kb < NBLKY; kb++) {
        if (tileflag[mblk + kb] == 0) continue;   // A-tile exactly zero: skip
        int kk0 = kb * BN;
#pragma unroll
        for (int k2 = 0; k2 < BN; k2 += BK) {
            int kk = kk0 + k2;
#pragma unroll
            for (int c = 0; c < 2; c++) {
                int rl = wave * 32 + c * 16 + grow;
                gll16(Kb + (size_t)(m0 + rl) * NP + kk + gcol,
                      &sA[(wave * 32 + c * 16) * LDSS]);
                const float* gp = Kinv + (size_t)(t0 + rl) * NP + kk + gcol;
                float4 v0 = *(const float4*)gp;
                float4 v1 = *(const float4*)(gp + 4);
                unsigned short tmp[8];
                tmp[0] = f2bf(v0.x); tmp[1] = f2bf(v0.y);
                tmp[2] = f2bf(v0.z); tmp[3] = f2bf(v0.w);
                tmp[4] = f2bf(v1.x); tmp[5] = f2bf(v1.y);
                tmp[6] = f2bf(v1.z); tmp[7] = f2bf(v1.w);
                *(uint4*)(&sB[rl * LDSS + gcol]) = *(const uint4*)tmp;
            }
            __syncthreads();
            frag8 af[4], bfr[4];
#pragma unroll
            for (int i = 0; i < 4; i++) {
                af[i]  = *(const frag8*)(&sA[(wr * 64 + i * 16 + rr) * LDSS + q * 8]);
                bfr[i] = *(const frag8*)(&sB[(wc * 64 + i * 16 + rr) * LDSS + q * 8]);
            }
#pragma unroll
            for (int i = 0; i < 4; i++)
#pragma unroll
                for (int j = 0; j < 4; j++)
                    acc[i][j] = __builtin_amdgcn_mfma_f32_16x16x32_bf16(af[i], bfr[j], acc[i][j], 0, 0, 0);
            __syncthreads();
        }
    }
    if (tileflag[mblk + blockIdx.y] == 0) return;  // Kb[m][t] block zero -> s == 0
#pragma unroll
    for (int i = 0; i < 4; i++) {
#pragma unroll
        for (int reg = 0; reg < 4; reg++) {
            int m = m0 + wr * 64 + i * 16 + q * 4 + reg;
            float s = 0.f;
#pragma unroll
            for (int j = 0; j < 4; j++) {
                int t = t0 + wc * 64 + j * 16 + rr;
                s += acc[i][j][reg] * bf2f(Kb[(size_t)m * NP + t]);
            }
            s += __shfl_xor(s, 1, 64);
            s += __shfl_xor(s, 2, 64);
            s += __shfl_xor(s, 4, 64);
            s += __shfl_xor(s, 8, 64);
            if (rr == 0 && s != 0.0f) atomicAdd(&q_acc[m], s);
        }
    }
}

__global__ void finalize(const float* __restrict__ q_acc, float* __restrict__ out) {
    int m = blockIdx.x * blockDim.x + threadIdx.x;
    if (m < R_ROWS) out[R_ROWS + m] = 1.0f - q_acc[m];
}

extern "C" void kernel_launch(void* const* d_in, const int* in_sizes, int n_in,
                              void* d_out, int out_size, void* d_ws, size_t ws_size,
                              hipStream_t stream) {
    const float* X     = (const float*)d_in[0];
    const int*   A     = (const int*)d_in[1];
    const float* Z     = (const float*)d_in[2];   // XA_train [4096][257]
    const float* alpha = (const float*)d_in[3];
    const float* Kinv  = (const float*)d_in[4];
    float* out = (float*)d_out;

    // workspace carve; total ~74.3 MB
    char* ws = (char*)d_ws;
    unsigned short* XAb = (unsigned short*)(ws);                 //  4,718,592 B
    unsigned short* Zb  = (unsigned short*)(ws + 4718592);       //  2,359,296 B
    float* x2       = (float*)(ws + 7077888);                    //     32,768 B
    float* z2       = (float*)(ws + 7110656);                    //     16,384 B
    // contiguous zero region: q_acc | rowflag | tileflag = 41,472 B (zeroed in prep)
    float*        q_acc    = (float*)(ws + 7127040);             //     32,768 B
    int*          rowflag  = (int*)  (ws + 7159808);             //        256 B
    int*          tileflag = (int*)  (ws + 7160064);             //      8,192 B
    unsigned short* Kb = (unsigned short*)(ws + 7168512);        // 67,108,864 B

    prep_all<<<(R_ROWS + NP) / 4, 256, 0, stream>>>(X, A, Z, XAb, Zb, x2, z2,
                                                    (char*)q_acc, out);
    gemm_kxz<<<dim3(NBLKX, NBLKY), 256, 0, stream>>>(XAb, Zb, x2, z2, alpha, Kb,
                                                     out, rowflag, tileflag);
    gemm_q<<<dim3(NBLKX, NBLKY), 256, 0, stream>>>(Kb, Kinv, q_acc, rowflag, tileflag);
    finalize<<<R_ROWS / 256, 256, 0, stream>>>(q_acc, out);
}

// Round 6
// 127.855 us; speedup vs baseline: 1.3441x; 1.0202x over previous
//
#include <hip/hip_runtime.h>
#include <math.h>

// Problem constants (B=8, M=1024, P=256, N=4096)
#define R_ROWS 8192   // B*M rows of X-side
#define NP     4096   // train points
#define DREAL  257    // P+1; feature 256 (the A/z-last column) handled as rank-1 fp32 term
#define DPAD   256    // MFMA K: 2 phases x 4 slabs x 32

#define BM 128
#define BN 128
#define BK 32
#define LDSS 32       // packed rows (global_load_lds-compatible)
#define NBLKX (R_ROWS / BM)   // 64
#define NBLKY (NP / BN)       // 32

using frag8 = __attribute__((ext_vector_type(8))) short;
using f32x4 = __attribute__((ext_vector_type(4))) float;

static __device__ __forceinline__ float bf2f(unsigned short u) {
    return __uint_as_float(((unsigned int)u) << 16);
}
static __device__ __forceinline__ unsigned short f2bf(float f) {
    unsigned int u = __float_as_uint(f);
    unsigned int lsb = (u >> 16) & 1u;
    u += 0x7fffu + lsb;           // round-to-nearest-even
    return (unsigned short)(u >> 16);
}

// async global->LDS, 16B per lane; lds base wave-uniform (lane i -> base + i*16B)
static __device__ __forceinline__ void gll16(const unsigned short* g, unsigned short* l) {
    __builtin_amdgcn_global_load_lds(
        (const __attribute__((address_space(1))) unsigned int*)g,
        (__attribute__((address_space(3))) unsigned int*)l, 16, 0, 0);
}

// ---- prep: bf16 [row][256] features + fp32 norms + rank-1 columns + out/flag init ----
__global__ void prep_all(const float* __restrict__ X, const int* __restrict__ A,
                         const float* __restrict__ Z,
                         unsigned short* __restrict__ XAb, unsigned short* __restrict__ Zb,
                         float* __restrict__ x2, float* __restrict__ z2,
                         float* __restrict__ zlast, float* __restrict__ af,
                         char* __restrict__ flags,   // rowflag|tileflag : 8448 B
                         float* __restrict__ out) {
    int b = blockIdx.x;
    int tid = threadIdx.x;
    if (b < 3) {                       // zero flags region
        int off = b * 4096 + tid * 16;
        uint4 zz = {0, 0, 0, 0};
        if (off < 8448) *(uint4*)(flags + off) = zz;
    } else if (b < 11) {               // f_loc accum region = 0
        int off = (b - 3) * 1024 + tid * 4;
        float4 zz4 = {0.f, 0.f, 0.f, 0.f};
        *(float4*)(out + off) = zz4;
    } else if (b < 19) {               // f_var region = 1 (gemm_q subtracts)
        int off = R_ROWS + (b - 11) * 1024 + tid * 4;
        float4 oo = {1.f, 1.f, 1.f, 1.f};
        *(float4*)(out + off) = oo;
    }

    int row  = b * 4 + (tid >> 6);
    int lane = tid & 63;
    float s = 0.f;
    if (row < R_ROWS) {
        const float* xr = X + (size_t)row * 256;
        unsigned short* o = XAb + (size_t)row * 256;
#pragma unroll
        for (int i = 0; i < 4; i++) {
            float v = xr[lane + 64 * i];
            s += v * v;
            o[lane + 64 * i] = f2bf(v);
        }
        if (lane == 0) {
            float a = (float)A[row];    // 0 or 1: exact in bf16/fp32
            af[row] = a;
            s += a * a;
        }
#pragma unroll
        for (int off = 32; off; off >>= 1) s += __shfl_down(s, off, 64);
        if (lane == 0) x2[row] = s;
    } else {
        int zi = row - R_ROWS;
        if (zi >= NP) return;
        const float* zr = Z + (size_t)zi * DREAL;
        unsigned short* o = Zb + (size_t)zi * 256;
#pragma unroll
        for (int i = 0; i < 4; i++) {
            float v = zr[lane + 64 * i];
            s += v * v;
            o[lane + 64 * i] = f2bf(v);
        }
        if (lane == 0) {
            float v = zr[256];
            s += v * v;
            zlast[zi] = bf2f(f2bf(v));  // bf16-quantized, consistent with GEMM precision
        }
#pragma unroll
        for (int off = 32; off; off >>= 1) s += __shfl_down(s, off, 64);
        if (lane == 0) z2[zi] = s;
    }
}

// ---- Kxz tile kernel: 2 phases x 4 slabs (64 MFMA/barrier), rank-1 fix-up, screen ----
__global__ __launch_bounds__(256, 2) void gemm_kxz(
    const unsigned short* __restrict__ Abuf,  // [R_ROWS][256]
    const unsigned short* __restrict__ Bbuf,  // [NP][256]
    const float* __restrict__ x2, const float* __restrict__ z2,
    const float* __restrict__ zlast, const float* __restrict__ af,
    const float* __restrict__ alpha,
    unsigned short* __restrict__ Kb,          // [R_ROWS][NP] (written only if needed)
    float* __restrict__ floc_out,             // [R_ROWS] pre-zeroed; atomic accum
    int* __restrict__ rowflag, int* __restrict__ tileflag)
{
    __shared__ unsigned short sh[2][4][BM * LDSS];   // A/B x 4 slabs x 8 KB = 64 KB exactly
    const int m0 = blockIdx.x * BM, n0 = blockIdx.y * BN;
    const int tid = threadIdx.x, lane = tid & 63, wave = tid >> 6;
    const int wr = wave >> 1, wc = wave & 1;
    const int q = lane >> 4, rr = lane & 15;
    const int grow = lane >> 2, gcol = (lane & 3) * 8;   // async staging lane map

    f32x4 acc[4][4] = {};
#pragma unroll
    for (int ph = 0; ph < 2; ph++) {
        int k0 = ph * 128;
#pragma unroll
        for (int s3 = 0; s3 < 4; s3++) {
            int ks = k0 + s3 * BK;
#pragma unroll
            for (int c = 0; c < 2; c++) {
                int r = wave * 32 + c * 16 + grow;
                gll16(Abuf + (size_t)(m0 + r) * 256 + ks + gcol,
                      &sh[0][s3][(wave * 32 + c * 16) * LDSS]);
                gll16(Bbuf + (size_t)(n0 + r) * 256 + ks + gcol,
                      &sh[1][s3][(wave * 32 + c * 16) * LDSS]);
            }
        }
        __syncthreads();
#pragma unroll
        for (int s3 = 0; s3 < 4; s3++) {
            frag8 afr[4], bfr[4];
#pragma unroll
            for (int i = 0; i < 4; i++) {
                afr[i] = *(const frag8*)(&sh[0][s3][(wr * 64 + i * 16 + rr) * LDSS + q * 8]);
                bfr[i] = *(const frag8*)(&sh[1][s3][(wc * 64 + i * 16 + rr) * LDSS + q * 8]);
            }
#pragma unroll
            for (int i = 0; i < 4; i++)
#pragma unroll
                for (int j = 0; j < 4; j++)
                    acc[i][j] = __builtin_amdgcn_mfma_f32_16x16x32_bf16(afr[i], bfr[j], acc[i][j], 0, 0, 0);
        }
        __syncthreads();
    }
    // ---- zero screen: bv==0 exactly iff d >= ~185.7 (half bf16 min-subnormal) ----
    float zn[4], zl[4];
#pragma unroll
    for (int j = 0; j < 4; j++) {
        int n = n0 + wc * 64 + j * 16 + rr;
        zn[j] = z2[n];
        zl[j] = zlast[n];
    }
    bool anyl = false;
#pragma unroll
    for (int i = 0; i < 4; i++)
#pragma unroll
        for (int reg = 0; reg < 4; reg++) {
            int ml = wr * 64 + i * 16 + q * 4 + reg;
            float x  = x2[m0 + ml];
            float am = af[m0 + ml];
#pragma unroll
            for (int j = 0; j < 4; j++) {
                float xz = fmaf(am, zl[j], acc[i][j][reg]);   // rank-1 K=256 term
                float d = x + zn[j] - 2.0f * xz;
                anyl |= !(d >= 186.0f);    // NaN-safe: NaN -> slow path
            }
        }
    // cross-wave OR through reused LDS (all frag reads completed at last barrier)
    unsigned long long wb = __ballot(anyl);
    int* sflag = (int*)&sh[0][0][0];
    if (lane == 0) sflag[wave] = (wb != 0ULL) ? 1 : 0;
    __syncthreads();
    if (sflag[0] | sflag[1] | sflag[2] | sflag[3]) {
        // exact epilogue (rare path): exp, Kb write, fused f_loc, flags
        float av[4];
#pragma unroll
        for (int j = 0; j < 4; j++) av[j] = alpha[n0 + wc * 64 + j * 16 + rr];
        unsigned int wany = 0;
#pragma unroll
        for (int i = 0; i < 4; i++) {
#pragma unroll
            for (int reg = 0; reg < 4; reg++) {
                int ml = wr * 64 + i * 16 + q * 4 + reg;
                float x  = x2[m0 + ml];
                float am = af[m0 + ml];
                float s = 0.f;
#pragma unroll
                for (int j = 0; j < 4; j++) {
                    float xz = fmaf(am, zl[j], acc[i][j][reg]);
                    float d = fmaxf(x + zn[j] - 2.0f * xz, 0.0f);
                    unsigned short bv = f2bf(__expf(-0.5f * d));
                    wany |= bv;
                    Kb[(size_t)(m0 + ml) * NP + n0 + wc * 64 + j * 16 + rr] = bv;
                    s += bf2f(bv) * av[j];
                }
                s += __shfl_xor(s, 1, 64);
                s += __shfl_xor(s, 2, 64);
                s += __shfl_xor(s, 4, 64);
                s += __shfl_xor(s, 8, 64);
                if (rr == 0 && s != 0.0f) atomicAdd(&floc_out[m0 + ml], s);
            }
        }
        unsigned long long b2 = __ballot(wany != 0);
        if (lane == 0 && b2 != 0ULL) {
            atomicOr(&tileflag[blockIdx.x * NBLKY + blockIdx.y], 1);
            atomicOr(&rowflag[blockIdx.x], 1);
        }
    }
}

// ---- out_var[m] -= sum_t (sum_n Kb[m][n]*bf16(Kinv[t][n])) * Kb[m][t]; tile-gated ----
__global__ __launch_bounds__(256, 4) void gemm_q(
    const unsigned short* __restrict__ Kb,   // [R_ROWS][NP] bf16 (sparse-tiled)
    const float* __restrict__ Kinv,          // [NP][NP] fp32, cast during staging
    float* __restrict__ out,                 // var half pre-initialized to 1.0
    const int* __restrict__ rowflag, const int* __restrict__ tileflag)
{
    const int m0 = blockIdx.x * BM, t0 = blockIdx.y * BN;
    if (rowflag[blockIdx.x] == 0) return;    // entire A row-block zero -> exact 0

    __shared__ unsigned short sA[BM * LDSS];
    __shared__ unsigned short sB[BN * LDSS];
    const int tid = threadIdx.x, lane = tid & 63, wave = tid >> 6;
    const int wr = wave >> 1, wc = wave & 1;
    const int q = lane >> 4, rr = lane & 15;
    const int grow = lane >> 2, gcol = (lane & 3) * 8;
    const int mblk = blockIdx.x * NBLKY;

    f32x4 acc[4][4] = {};
    for (int kb = 0; kb < NBLKY; kb++) {
        if (tileflag[mblk + kb] == 0) continue;   // A-tile exactly zero: skip
        int kk0 = kb * BN;
#pragma unroll
        for (int k2 = 0; k2 < BN; k2 += BK) {
            int kk = kk0 + k2;
#pragma unroll
            for (int c = 0; c < 2; c++) {
                int rl = wave * 32 + c * 16 + grow;
                gll16(Kb + (size_t)(m0 + rl) * NP + kk + gcol,
                      &sA[(wave * 32 + c * 16) * LDSS]);
                const float* gp = Kinv + (size_t)(t0 + rl) * NP + kk + gcol;
                float4 v0 = *(const float4*)gp;
                float4 v1 = *(const float4*)(gp + 4);
                unsigned short tmp[8];
                tmp[0] = f2bf(v0.x); tmp[1] = f2bf(v0.y);
                tmp[2] = f2bf(v0.z); tmp[3] = f2bf(v0.w);
                tmp[4] = f2bf(v1.x); tmp[5] = f2bf(v1.y);
                tmp[6] = f2bf(v1.z); tmp[7] = f2bf(v1.w);
                *(uint4*)(&sB[rl * LDSS + gcol]) = *(const uint4*)tmp;
            }
            __syncthreads();
            frag8 afr[4], bfr[4];
#pragma unroll
            for (int i = 0; i < 4; i++) {
                afr[i] = *(const frag8*)(&sA[(wr * 64 + i * 16 + rr) * LDSS + q * 8]);
                bfr[i] = *(const frag8*)(&sB[(wc * 64 + i * 16 + rr) * LDSS + q * 8]);
            }
#pragma unroll
            for (int i = 0; i < 4; i++)
#pragma unroll
                for (int j = 0; j < 4; j++)
                    acc[i][j] = __builtin_amdgcn_mfma_f32_16x16x32_bf16(afr[i], bfr[j], acc[i][j], 0, 0, 0);
            __syncthreads();
        }
    }
    if (tileflag[mblk + blockIdx.y] == 0) return;  // Kb[m][t] block zero -> s == 0
#pragma unroll
    for (int i = 0; i < 4; i++) {
#pragma unroll
        for (int reg = 0; reg < 4; reg++) {
            int m = m0 + wr * 64 + i * 16 + q * 4 + reg;
            float s = 0.f;
#pragma unroll
            for (int j = 0; j < 4; j++) {
                int t = t0 + wc * 64 + j * 16 + rr;
                s += acc[i][j][reg] * bf2f(Kb[(size_t)m * NP + t]);
            }
            s += __shfl_xor(s, 1, 64);
            s += __shfl_xor(s, 2, 64);
            s += __shfl_xor(s, 4, 64);
            s += __shfl_xor(s, 8, 64);
            if (rr == 0 && s != 0.0f) atomicAdd(&out[R_ROWS + m], -s);   // f_var = 1 - q
        }
    }
}

extern "C" void kernel_launch(void* const* d_in, const int* in_sizes, int n_in,
                              void* d_out, int out_size, void* d_ws, size_t ws_size,
                              hipStream_t stream) {
    const float* X     = (const float*)d_in[0];
    const int*   A     = (const int*)d_in[1];
    const float* Z     = (const float*)d_in[2];   // XA_train [4096][257]
    const float* alpha = (const float*)d_in[3];
    const float* Kinv  = (const float*)d_in[4];
    float* out = (float*)d_out;

    // workspace carve; total ~70.1 MB
    char* ws = (char*)d_ws;
    unsigned short* XAb = (unsigned short*)(ws);                 //  4,194,304 B
    unsigned short* Zb  = (unsigned short*)(ws + 4194304);       //  2,097,152 B
    float* x2    = (float*)(ws + 6291456);                       //     32,768 B
    float* z2    = (float*)(ws + 6324224);                       //     16,384 B
    float* zlast = (float*)(ws + 6340608);                       //     16,384 B
    float* af    = (float*)(ws + 6356992);                       //     32,768 B
    int*   rowflag  = (int*)(ws + 6389760);                      //        256 B
    int*   tileflag = (int*)(ws + 6390016);                      //      8,192 B
    unsigned short* Kb = (unsigned short*)(ws + 6398208);        // 67,108,864 B

    prep_all<<<(R_ROWS + NP) / 4, 256, 0, stream>>>(X, A, Z, XAb, Zb, x2, z2, zlast, af,
                                                    (char*)rowflag, out);
    gemm_kxz<<<dim3(NBLKX, NBLKY), 256, 0, stream>>>(XAb, Zb, x2, z2, zlast, af, alpha,
                                                     Kb, out, rowflag, tileflag);
    gemm_q<<<dim3(NBLKX, NBLKY), 256, 0, stream>>>(Kb, Kinv, out, rowflag, tileflag);
}

// Round 7
// 126.493 us; speedup vs baseline: 1.3586x; 1.0108x over previous
//
#include <hip/hip_runtime.h>
#include <math.h>

// Problem constants (B=8, M=1024, P=256, N=4096)
#define R_ROWS 8192   // B*M rows of X-side
#define NP     4096   // train points
#define DREAL  257    // P+1; feature 256 handled as rank-1 fp32 term in epilogue
#define KDIM   256    // MFMA K

#define BM 256        // kxz row-tile
#define BN 128        // kxz col-tile
#define BK 32
#define LDSS 32       // packed rows (global_load_lds-compatible)
#define MB256 (R_ROWS / BM)   // 32 row-blocks (256 rows each)
#define NB128 (NP / BN)       // 32 col-blocks

using frag8 = __attribute__((ext_vector_type(8))) short;
using f32x4 = __attribute__((ext_vector_type(4))) float;

static __device__ __forceinline__ float bf2f(unsigned short u) {
    return __uint_as_float(((unsigned int)u) << 16);
}
static __device__ __forceinline__ unsigned short f2bf(float f) {
    unsigned int u = __float_as_uint(f);
    unsigned int lsb = (u >> 16) & 1u;
    u += 0x7fffu + lsb;           // round-to-nearest-even
    return (unsigned short)(u >> 16);
}

// async global->LDS, 16B per lane; lds base wave-uniform (lane i -> base + i*16B)
static __device__ __forceinline__ void gll16(const unsigned short* g, unsigned short* l) {
    __builtin_amdgcn_global_load_lds(
        (const __attribute__((address_space(1))) unsigned int*)g,
        (__attribute__((address_space(3))) unsigned int*)l, 16, 0, 0);
}

// ---- prep: bf16 [row][256] features + fp32 norms + rank-1 columns + out/flag init ----
__global__ void prep_all(const float* __restrict__ X, const int* __restrict__ A,
                         const float* __restrict__ Z,
                         unsigned short* __restrict__ XAb, unsigned short* __restrict__ Zb,
                         float* __restrict__ x2, float* __restrict__ z2,
                         float* __restrict__ zlast, float* __restrict__ af,
                         char* __restrict__ flags,   // rowflag|tileflag : 8448 B
                         float* __restrict__ out) {
    int b = blockIdx.x;
    int tid = threadIdx.x;
    if (b < 3) {                       // zero flags region
        int off = b * 4096 + tid * 16;
        uint4 zz = {0, 0, 0, 0};
        if (off < 8448) *(uint4*)(flags + off) = zz;
    } else if (b < 11) {               // f_loc accum region = 0
        int off = (b - 3) * 1024 + tid * 4;
        float4 zz4 = {0.f, 0.f, 0.f, 0.f};
        *(float4*)(out + off) = zz4;
    } else if (b < 19) {               // f_var region = 1 (gemm_q subtracts)
        int off = R_ROWS + (b - 11) * 1024 + tid * 4;
        float4 oo = {1.f, 1.f, 1.f, 1.f};
        *(float4*)(out + off) = oo;
    }

    int row  = b * 4 + (tid >> 6);
    int lane = tid & 63;
    float s = 0.f;
    if (row < R_ROWS) {
        const float* xr = X + (size_t)row * 256;
        unsigned short* o = XAb + (size_t)row * 256;
        float4 v = *(const float4*)(xr + lane * 4);       // one dwordx4 per lane
        s = v.x * v.x + v.y * v.y + v.z * v.z + v.w * v.w;
        ushort4 p = {f2bf(v.x), f2bf(v.y), f2bf(v.z), f2bf(v.w)};
        *(ushort4*)(o + lane * 4) = p;
        if (lane == 0) {
            float a = (float)A[row];    // 0 or 1: exact in bf16/fp32
            af[row] = a;
            s += a * a;
        }
#pragma unroll
        for (int off = 32; off; off >>= 1) s += __shfl_down(s, off, 64);
        if (lane == 0) x2[row] = s;
    } else {
        int zi = row - R_ROWS;
        if (zi >= NP) return;
        const float* zr = Z + (size_t)zi * DREAL;
        unsigned short* o = Zb + (size_t)zi * 256;
        // Z rows are 257-stride: only 4B-aligned guaranteed -> float loads
        float4 v;
        v.x = zr[lane * 4 + 0]; v.y = zr[lane * 4 + 1];
        v.z = zr[lane * 4 + 2]; v.w = zr[lane * 4 + 3];
        s = v.x * v.x + v.y * v.y + v.z * v.z + v.w * v.w;
        ushort4 p = {f2bf(v.x), f2bf(v.y), f2bf(v.z), f2bf(v.w)};
        *(ushort4*)(o + lane * 4) = p;
        if (lane == 0) {
            float v256 = zr[256];
            s += v256 * v256;
            zlast[zi] = bf2f(f2bf(v256));  // bf16-quantized, consistent with GEMM
        }
#pragma unroll
        for (int off = 32; off; off >>= 1) s += __shfl_down(s, off, 64);
        if (lane == 0) z2[zi] = s;
    }
}

// ---- Kxz tile kernel: 256x128 tile, 4 phases x 2 slabs, rank-1 fix-up, screen ----
__global__ __launch_bounds__(256, 2) void gemm_kxz(
    const unsigned short* __restrict__ Abuf,  // [R_ROWS][256]
    const unsigned short* __restrict__ Bbuf,  // [NP][256]
    const float* __restrict__ x2, const float* __restrict__ z2,
    const float* __restrict__ zlast, const float* __restrict__ af,
    const float* __restrict__ alpha,
    unsigned short* __restrict__ Kb,          // [R_ROWS][NP] (written only if needed)
    float* __restrict__ floc_out,             // [R_ROWS] pre-zeroed; atomic accum
    int* __restrict__ rowflag, int* __restrict__ tileflag)
{
    __shared__ unsigned short sA[2][BM * LDSS];   // 2 x 16 KB
    __shared__ unsigned short sB[2][BN * LDSS];   // 2 x  8 KB   (48 KB total)
    __shared__ int sflag[4];
    const int m0 = blockIdx.x * BM, n0 = blockIdx.y * BN;
    const int tid = threadIdx.x, lane = tid & 63, wave = tid >> 6;
    const int wr = wave >> 1, wc = wave & 1;      // wr: 128-row strip, wc: 64-col strip
    const int q = lane >> 4, rr = lane & 15;
    const int grow = lane >> 2, gcol = (lane & 3) * 8;   // async staging lane map

    f32x4 acc[8][4] = {};
#pragma unroll
    for (int ph = 0; ph < 4; ph++) {
        int k0 = ph * 64;
#pragma unroll
        for (int s2 = 0; s2 < 2; s2++) {
            int ks = k0 + s2 * BK;
#pragma unroll
            for (int c = 0; c < 4; c++) {        // A: 256 rows, 16/call, 4 calls/wave
                int r = wave * 64 + c * 16 + grow;
                gll16(Abuf + (size_t)(m0 + r) * 256 + ks + gcol,
                      &sA[s2][(wave * 64 + c * 16) * LDSS]);
            }
#pragma unroll
            for (int c = 0; c < 2; c++) {        // B: 128 rows, 2 calls/wave
                int r = wave * 32 + c * 16 + grow;
                gll16(Bbuf + (size_t)(n0 + r) * 256 + ks + gcol,
                      &sB[s2][(wave * 32 + c * 16) * LDSS]);
            }
        }
        __syncthreads();
#pragma unroll
        for (int s2 = 0; s2 < 2; s2++) {
            frag8 afr[8], bfr[4];
#pragma unroll
            for (int i = 0; i < 8; i++)
                afr[i] = *(const frag8*)(&sA[s2][(wr * 128 + i * 16 + rr) * LDSS + q * 8]);
#pragma unroll
            for (int j = 0; j < 4; j++)
                bfr[j] = *(const frag8*)(&sB[s2][(wc * 64 + j * 16 + rr) * LDSS + q * 8]);
#pragma unroll
            for (int i = 0; i < 8; i++)
#pragma unroll
                for (int j = 0; j < 4; j++)
                    acc[i][j] = __builtin_amdgcn_mfma_f32_16x16x32_bf16(afr[i], bfr[j], acc[i][j], 0, 0, 0);
        }
        __syncthreads();
    }
    // ---- zero screen: bv==0 exactly iff d >= ~185.7 (half bf16 min-subnormal) ----
    float zn[4], zl[4];
#pragma unroll
    for (int j = 0; j < 4; j++) {
        int n = n0 + wc * 64 + j * 16 + rr;
        zn[j] = z2[n];
        zl[j] = zlast[n];
    }
    bool anyl = false;
#pragma unroll
    for (int i = 0; i < 8; i++)
#pragma unroll
        for (int reg = 0; reg < 4; reg++) {
            int ml = wr * 128 + i * 16 + q * 4 + reg;
            float x  = x2[m0 + ml];
            float am = af[m0 + ml];
#pragma unroll
            for (int j = 0; j < 4; j++) {
                float xz = fmaf(am, zl[j], acc[i][j][reg]);   // rank-1 K=256 term
                float d = x + zn[j] - 2.0f * xz;
                anyl |= !(d >= 186.0f);    // NaN-safe: NaN -> slow path
            }
        }
    unsigned long long wb = __ballot(anyl);
    if (lane == 0) sflag[wave] = (wb != 0ULL) ? 1 : 0;
    __syncthreads();
    if (sflag[0] | sflag[1] | sflag[2] | sflag[3]) {
        // exact epilogue (rare path): exp, Kb write, fused f_loc, flags
        float av[4];
#pragma unroll
        for (int j = 0; j < 4; j++) av[j] = alpha[n0 + wc * 64 + j * 16 + rr];
        unsigned int wany = 0;
#pragma unroll
        for (int i = 0; i < 8; i++) {
#pragma unroll
            for (int reg = 0; reg < 4; reg++) {
                int ml = wr * 128 + i * 16 + q * 4 + reg;
                float x  = x2[m0 + ml];
                float am = af[m0 + ml];
                float s = 0.f;
#pragma unroll
                for (int j = 0; j < 4; j++) {
                    float xz = fmaf(am, zl[j], acc[i][j][reg]);
                    float d = fmaxf(x + zn[j] - 2.0f * xz, 0.0f);
                    unsigned short bv = f2bf(__expf(-0.5f * d));
                    wany |= bv;
                    Kb[(size_t)(m0 + ml) * NP + n0 + wc * 64 + j * 16 + rr] = bv;
                    s += bf2f(bv) * av[j];
                }
                s += __shfl_xor(s, 1, 64);
                s += __shfl_xor(s, 2, 64);
                s += __shfl_xor(s, 4, 64);
                s += __shfl_xor(s, 8, 64);
                if (rr == 0 && s != 0.0f) atomicAdd(&floc_out[m0 + ml], s);
            }
        }
        unsigned long long b2 = __ballot(wany != 0);
        if (lane == 0 && b2 != 0ULL) {
            atomicOr(&tileflag[blockIdx.x * NB128 + blockIdx.y], 1);
            atomicOr(&rowflag[blockIdx.x], 1);
        }
    }
}

// ---- out_var[m] -= sum_t (sum_n Kb[m][n]*bf16(Kinv[t][n])) * Kb[m][t]; tile-gated ----
// 128x128 tiles; flag indices are 256-row granular (>>1 mapping) — exactness preserved.
__global__ __launch_bounds__(256, 4) void gemm_q(
    const unsigned short* __restrict__ Kb,   // [R_ROWS][NP] bf16 (sparse-tiled)
    const float* __restrict__ Kinv,          // [NP][NP] fp32, cast during staging
    float* __restrict__ out,                 // var half pre-initialized to 1.0
    const int* __restrict__ rowflag, const int* __restrict__ tileflag)
{
    const int mrow = blockIdx.x >> 1;        // 256-row flag block
    if (rowflag[mrow] == 0) return;          // entire A row-block zero -> exact 0
    const int m0 = blockIdx.x * 128, t0 = blockIdx.y * BN;

    __shared__ unsigned short sA[128 * LDSS];
    __shared__ unsigned short sB[BN * LDSS];
    const int tid = threadIdx.x, lane = tid & 63, wave = tid >> 6;
    const int wr = wave >> 1, wc = wave & 1;
    const int q = lane >> 4, rr = lane & 15;
    const int grow = lane >> 2, gcol = (lane & 3) * 8;

    f32x4 acc[4][4] = {};
    for (int kb = 0; kb < NB128; kb++) {
        if (tileflag[mrow * NB128 + kb] == 0) continue;   // region exactly zero: skip
        int kk0 = kb * BN;
#pragma unroll
        for (int k2 = 0; k2 < BN; k2 += BK) {
            int kk = kk0 + k2;
#pragma unroll
            for (int c = 0; c < 2; c++) {
                int rl = wave * 32 + c * 16 + grow;
                gll16(Kb + (size_t)(m0 + rl) * NP + kk + gcol,
                      &sA[(wave * 32 + c * 16) * LDSS]);
                const float* gp = Kinv + (size_t)(t0 + rl) * NP + kk + gcol;
                float4 v0 = *(const float4*)gp;
                float4 v1 = *(const float4*)(gp + 4);
                unsigned short tmp[8];
                tmp[0] = f2bf(v0.x); tmp[1] = f2bf(v0.y);
                tmp[2] = f2bf(v0.z); tmp[3] = f2bf(v0.w);
                tmp[4] = f2bf(v1.x); tmp[5] = f2bf(v1.y);
                tmp[6] = f2bf(v1.z); tmp[7] = f2bf(v1.w);
                *(uint4*)(&sB[rl * LDSS + gcol]) = *(const uint4*)tmp;
            }
            __syncthreads();
            frag8 afr[4], bfr[4];
#pragma unroll
            for (int i = 0; i < 4; i++) {
                afr[i] = *(const frag8*)(&sA[(wr * 64 + i * 16 + rr) * LDSS + q * 8]);
                bfr[i] = *(const frag8*)(&sB[(wc * 64 + i * 16 + rr) * LDSS + q * 8]);
            }
#pragma unroll
            for (int i = 0; i < 4; i++)
#pragma unroll
                for (int j = 0; j < 4; j++)
                    acc[i][j] = __builtin_amdgcn_mfma_f32_16x16x32_bf16(afr[i], bfr[j], acc[i][j], 0, 0, 0);
            __syncthreads();
        }
    }
    if (tileflag[mrow * NB128 + blockIdx.y] == 0) return;  // Kb[m][t] region zero
#pragma unroll
    for (int i = 0; i < 4; i++) {
#pragma unroll
        for (int reg = 0; reg < 4; reg++) {
            int m = m0 + wr * 64 + i * 16 + q * 4 + reg;
            float s = 0.f;
#pragma unroll
            for (int j = 0; j < 4; j++) {
                int t = t0 + wc * 64 + j * 16 + rr;
                s += acc[i][j][reg] * bf2f(Kb[(size_t)m * NP + t]);
            }
            s += __shfl_xor(s, 1, 64);
            s += __shfl_xor(s, 2, 64);
            s += __shfl_xor(s, 4, 64);
            s += __shfl_xor(s, 8, 64);
            if (rr == 0 && s != 0.0f) atomicAdd(&out[R_ROWS + m], -s);   // f_var = 1 - q
        }
    }
}

extern "C" void kernel_launch(void* const* d_in, const int* in_sizes, int n_in,
                              void* d_out, int out_size, void* d_ws, size_t ws_size,
                              hipStream_t stream) {
    const float* X     = (const float*)d_in[0];
    const int*   A     = (const int*)d_in[1];
    const float* Z     = (const float*)d_in[2];   // XA_train [4096][257]
    const float* alpha = (const float*)d_in[3];
    const float* Kinv  = (const float*)d_in[4];
    float* out = (float*)d_out;

    // workspace carve; total ~70.1 MB
    char* ws = (char*)d_ws;
    unsigned short* XAb = (unsigned short*)(ws);                 //  4,194,304 B
    unsigned short* Zb  = (unsigned short*)(ws + 4194304);       //  2,097,152 B
    float* x2    = (float*)(ws + 6291456);                       //     32,768 B
    float* z2    = (float*)(ws + 6324224);                       //     16,384 B
    float* zlast = (float*)(ws + 6340608);                       //     16,384 B
    float* af    = (float*)(ws + 6356992);                       //     32,768 B
    int*   rowflag  = (int*)(ws + 6389760);                      //        256 B (32 used)
    int*   tileflag = (int*)(ws + 6390016);                      //      8,192 B (32x32 used)
    unsigned short* Kb = (unsigned short*)(ws + 6398208);        // 67,108,864 B

    prep_all<<<(R_ROWS + NP) / 4, 256, 0, stream>>>(X, A, Z, XAb, Zb, x2, z2, zlast, af,
                                                    (char*)rowflag, out);
    gemm_kxz<<<dim3(MB256, NB128), 256, 0, stream>>>(XAb, Zb, x2, z2, zlast, af, alpha,
                                                     Kb, out, rowflag, tileflag);
    gemm_q<<<dim3(R_ROWS / 128, NB128), 256, 0, stream>>>(Kb, Kinv, out, rowflag, tileflag);
}